// Round 1
// baseline (324.450 us; speedup 1.0000x reference)
//
#include <hip/hip_runtime.h>
#include <math.h>

// Problem constants (from reference): B=32, F=2048, H=W=7 -> hw=49, A=1.
#define BB   32
#define FF   2048
#define HW   49
#define HWP  52      // 49 padded to 13 float4
#define E3   147     // 3*hw
#define FT   64      // f-tile in attn kernel
#define GT   64      // g-tile in attn kernel

// ---------------------------------------------------------------------------
// Stage A: qkv projection + fold v into scalar w = v . W_out
//   qt[b][d][f] = (x[b,f,:] . W_qkv[d,:]) * (1/7)      (scale folded into q)
//   kt[b][d][f] =  x[b,f,:] . W_qkv[49+d,:]
//   w [b][f]    = sum_d (x[b,f,:] . W_qkv[98+d,:]) * W_out[d]
// ---------------------------------------------------------------------------
__global__ __launch_bounds__(256) void qkvw_kernel(
    const float* __restrict__ x, const float* __restrict__ Wqkv,
    const float* __restrict__ Wout,
    float* __restrict__ qt, float* __restrict__ kt, float* __restrict__ w)
{
    __shared__ float Wsh[E3 * HWP];
    const int tid = threadIdx.x;
    for (int i = tid; i < E3 * HWP; i += 256) {
        int e = i / HWP, d = i - e * HWP;
        Wsh[i] = (d < HW) ? Wqkv[e * HW + d] : 0.f;
    }
    __syncthreads();

    const int r = blockIdx.x * 256 + tid;    // (b,f) row index in [0, B*F)
    const int b = r >> 11;
    const int f = r & (FF - 1);

    // x row into registers (padded with zeros to 52)
    float4 xr[13];
    const float* xrow = x + (size_t)r * HW;
    #pragma unroll
    for (int c = 0; c < 13; ++c) {
        float v0 = (c * 4 + 0 < HW) ? xrow[c * 4 + 0] : 0.f;
        float v1 = (c * 4 + 1 < HW) ? xrow[c * 4 + 1] : 0.f;
        float v2 = (c * 4 + 2 < HW) ? xrow[c * 4 + 2] : 0.f;
        float v3 = (c * 4 + 3 < HW) ? xrow[c * 4 + 3] : 0.f;
        xr[c] = make_float4(v0, v1, v2, v3);
    }

    const float4* Wsh4 = reinterpret_cast<const float4*>(Wsh);
    float wacc = 0.f;
    for (int e = 0; e < E3; ++e) {
        float4 a4 = make_float4(0.f, 0.f, 0.f, 0.f);
        #pragma unroll
        for (int c = 0; c < 13; ++c) {
            float4 wv = Wsh4[e * 13 + c];
            a4.x += xr[c].x * wv.x;
            a4.y += xr[c].y * wv.y;
            a4.z += xr[c].z * wv.z;
            a4.w += xr[c].w * wv.w;
        }
        float acc = (a4.x + a4.y) + (a4.z + a4.w);
        if (e < HW) {
            qt[((b * HW + e) << 11) + f] = acc * (1.f / 7.f);
        } else if (e < 2 * HW) {
            kt[((b * HW + (e - HW)) << 11) + f] = acc;
        } else {
            wacc += acc * Wout[e - 2 * HW];
        }
    }
    w[r] = wacc;
}

// ---------------------------------------------------------------------------
// Stage B: per (b, f): out_raw[b,f] = sum_g softmax_g(q[b,f].k[b,g]) * w[b,g]
// Flash-style online softmax with scalar "value" w. Block = (b, 64-f tile).
// 16x16 threads, each owns a 4x4 (f,g) score tile; per-thread-local online
// state over its own g-columns, one shfl merge across the 16 tx lanes at end.
// ---------------------------------------------------------------------------
__global__ __launch_bounds__(256) void attn_kernel(
    const float* __restrict__ qt, const float* __restrict__ kt,
    const float* __restrict__ w, float* __restrict__ raw)
{
    __shared__ float Qs[HW][FT];
    __shared__ float Ks[HW][GT];
    __shared__ float ws[GT];

    const int b  = blockIdx.y;
    const int f0 = blockIdx.x * FT;
    const int tid = threadIdx.x;
    const int tx = tid & 15;       // g group
    const int ty = tid >> 4;       // f group

    // load Q tile [49][64] (coalesced: 64-float contiguous rows)
    for (int i = tid; i < HW * FT; i += 256) {
        int d = i >> 6, j = i & 63;
        Qs[d][j] = qt[((b * HW + d) << 11) + f0 + j];
    }

    float m[4], l[4], a[4];
    #pragma unroll
    for (int i = 0; i < 4; ++i) { m[i] = -1e30f; l[i] = 0.f; a[i] = 0.f; }

    for (int t = 0; t < FF / GT; ++t) {
        const int g0 = t * GT;
        __syncthreads();   // previous tile's compute done (also covers Qs at t=0)
        for (int i = tid; i < HW * GT; i += 256) {
            int d = i >> 6, j = i & 63;
            Ks[d][j] = kt[((b * HW + d) << 11) + g0 + j];
        }
        if (tid < GT) ws[tid] = w[(b << 11) + g0 + tid];
        __syncthreads();

        float s[4][4];
        #pragma unroll
        for (int i = 0; i < 4; ++i)
            #pragma unroll
            for (int j = 0; j < 4; ++j) s[i][j] = 0.f;

        #pragma unroll
        for (int d = 0; d < HW; ++d) {
            float4 qv = *reinterpret_cast<const float4*>(&Qs[d][ty * 4]);
            float4 kv = *reinterpret_cast<const float4*>(&Ks[d][tx * 4]);
            s[0][0] += qv.x * kv.x; s[0][1] += qv.x * kv.y;
            s[0][2] += qv.x * kv.z; s[0][3] += qv.x * kv.w;
            s[1][0] += qv.y * kv.x; s[1][1] += qv.y * kv.y;
            s[1][2] += qv.y * kv.z; s[1][3] += qv.y * kv.w;
            s[2][0] += qv.z * kv.x; s[2][1] += qv.z * kv.y;
            s[2][2] += qv.z * kv.z; s[2][3] += qv.z * kv.w;
            s[3][0] += qv.w * kv.x; s[3][1] += qv.w * kv.y;
            s[3][2] += qv.w * kv.z; s[3][3] += qv.w * kv.w;
        }

        float4 wv = *reinterpret_cast<const float4*>(&ws[tx * 4]);
        #pragma unroll
        for (int i = 0; i < 4; ++i) {
            float mt = fmaxf(fmaxf(s[i][0], s[i][1]), fmaxf(s[i][2], s[i][3]));
            float mn = fmaxf(m[i], mt);
            float corr = __expf(m[i] - mn);
            float p0 = __expf(s[i][0] - mn);
            float p1 = __expf(s[i][1] - mn);
            float p2 = __expf(s[i][2] - mn);
            float p3 = __expf(s[i][3] - mn);
            l[i] = l[i] * corr + ((p0 + p1) + (p2 + p3));
            a[i] = a[i] * corr +
                   ((p0 * wv.x + p1 * wv.y) + (p2 * wv.z + p3 * wv.w));
            m[i] = mn;
        }
    }

    // merge the 16 tx-lane partial states per f row
    #pragma unroll
    for (int i = 0; i < 4; ++i) {
        #pragma unroll
        for (int off = 1; off < 16; off <<= 1) {
            float mo = __shfl_xor(m[i], off);
            float lo = __shfl_xor(l[i], off);
            float ao = __shfl_xor(a[i], off);
            float mn = fmaxf(m[i], mo);
            float c1 = __expf(m[i] - mn);
            float c2 = __expf(mo - mn);
            l[i] = l[i] * c1 + lo * c2;
            a[i] = a[i] * c1 + ao * c2;
            m[i] = mn;
        }
        if (tx == 0) raw[(b << 11) + f0 + ty * 4 + i] = a[i] / l[i];
    }
}

// ---------------------------------------------------------------------------
// Stage C: BatchNorm1d over [B, F, 1]: per-channel f stats over the 32 batch
// entries. b_out cancels (mean subtraction) so it was never added.
// ---------------------------------------------------------------------------
__global__ __launch_bounds__(256) void bn_kernel(
    const float* __restrict__ raw, const float* __restrict__ gamma,
    const float* __restrict__ beta, float* __restrict__ out)
{
    const int f = blockIdx.x * 256 + threadIdx.x;   // [0, 2048)
    float v[BB];
    float mean = 0.f;
    #pragma unroll
    for (int bb = 0; bb < BB; ++bb) {
        v[bb] = raw[(bb << 11) + f];
        mean += v[bb];
    }
    mean *= (1.f / BB);
    float var = 0.f;
    #pragma unroll
    for (int bb = 0; bb < BB; ++bb) {
        float d = v[bb] - mean;
        var += d * d;
    }
    var *= (1.f / BB);
    const float inv = rsqrtf(var + 1e-5f);
    const float g = gamma[f], be = beta[f];
    #pragma unroll
    for (int bb = 0; bb < BB; ++bb)
        out[(bb << 11) + f] = (v[bb] - mean) * inv * g + be;
}

// ---------------------------------------------------------------------------
extern "C" void kernel_launch(void* const* d_in, const int* in_sizes, int n_in,
                              void* d_out, int out_size, void* d_ws, size_t ws_size,
                              hipStream_t stream)
{
    const float* x     = (const float*)d_in[0];
    const float* Wqkv  = (const float*)d_in[1];
    const float* Wout  = (const float*)d_in[2];
    // d_in[3] = b_out: cancels exactly under BatchNorm mean subtraction.
    const float* gamma = (const float*)d_in[4];
    const float* beta  = (const float*)d_in[5];

    float* wsp = (float*)d_ws;
    float* qt  = wsp;                         // 32*49*2048
    float* kt  = qt + BB * HW * FF;           // 32*49*2048
    float* w   = kt + BB * HW * FF;           // 32*2048
    float* raw = w + BB * FF;                 // 32*2048
    // total: 26,214,400 bytes (25 MiB) of d_ws

    qkvw_kernel<<<dim3((BB * FF) / 256), dim3(256), 0, stream>>>(
        x, Wqkv, Wout, qt, kt, w);

    attn_kernel<<<dim3(FF / FT, BB), dim3(256), 0, stream>>>(qt, kt, w, raw);

    bn_kernel<<<dim3(FF / 256), dim3(256), 0, stream>>>(raw, gamma, beta,
                                                        (float*)d_out);
}

// Round 2
// 135.328 us; speedup vs baseline: 2.3975x; 2.3975x over previous
//
#include <hip/hip_runtime.h>
#include <math.h>

// Problem constants: B=32, F=2048, hw=49, A=1.
#define BB    32
#define FF    2048
#define HW    49
#define E3    147
#define DPAD  64          // d padded 49 -> 64 (zeros)
#define SPLIT 2           // g-range split per (b, f-tile)
#define GSTEP 32          // g rows per step (one 32x32 MFMA tile row)
#define FBLK  128         // f per block (4 waves x 32)
#define NSTEP ((FF / SPLIT) / GSTEP)   // 32

typedef float f32x16 __attribute__((ext_vector_type(16)));
typedef short bf16x8 __attribute__((ext_vector_type(8)));

// Split fp32 into bf16 hi + bf16 lo (both RNE), packed (hi<<16)|lo.
__device__ inline unsigned bf16pack(float v) {
    unsigned u = __float_as_uint(v);
    unsigned hi = (u + 0x7FFFu + ((u >> 16) & 1u)) >> 16;
    float hf = __uint_as_float(hi << 16);
    float lof = v - hf;
    unsigned ul = __float_as_uint(lof);
    unsigned lo = (ul + 0x7FFFu + ((ul >> 16) & 1u)) >> 16;
    return (hi << 16) | lo;
}

// ---------------------------------------------------------------------------
// Stage A: qkv projection -> bf16 hi/lo panels [row][64] + scalar w = v.W_out
// q is pre-scaled by 1/7 (the hw^-0.5 score scale). b_out cancels under BN.
// ---------------------------------------------------------------------------
__global__ __launch_bounds__(256) void qkvw_kernel(
    const float* __restrict__ x, const float* __restrict__ Wqkv,
    const float* __restrict__ Wout,
    unsigned short* __restrict__ qh, unsigned short* __restrict__ ql,
    unsigned short* __restrict__ kh, unsigned short* __restrict__ kl,
    float* __restrict__ wv)
{
    __shared__ float Wsh[E3 * 52];
    __shared__ unsigned tile[256 * 32];
    const int tid = threadIdx.x;
    const int r0 = blockIdx.x * 256;
    const int r = r0 + tid;

    for (int i = tid; i < E3 * 52; i += 256) {
        int e = i / 52, d = i - e * 52;
        Wsh[i] = (d < HW) ? Wqkv[e * HW + d] : 0.f;
    }

    float4 xr[13];
    const float* xrow = x + (size_t)r * HW;
    #pragma unroll
    for (int c = 0; c < 13; ++c) {
        float v0 = (c * 4 + 0 < HW) ? xrow[c * 4 + 0] : 0.f;
        float v1 = (c * 4 + 1 < HW) ? xrow[c * 4 + 1] : 0.f;
        float v2 = (c * 4 + 2 < HW) ? xrow[c * 4 + 2] : 0.f;
        float v3 = (c * 4 + 3 < HW) ? xrow[c * 4 + 3] : 0.f;
        xr[c] = make_float4(v0, v1, v2, v3);
    }
    __syncthreads();

    auto dot = [&](int e) -> float {
        const float4* W4 = (const float4*)(Wsh + e * 52);   // 208B rows, 16B aligned
        float ax = 0.f, ay = 0.f, az = 0.f, aw = 0.f;
        #pragma unroll
        for (int c = 0; c < 13; ++c) {
            float4 w4 = W4[c];
            ax = fmaf(xr[c].x, w4.x, ax);
            ay = fmaf(xr[c].y, w4.y, ay);
            az = fmaf(xr[c].z, w4.z, az);
            aw = fmaf(xr[c].w, w4.w, aw);
        }
        return (ax + ay) + (az + aw);
    };

    // one 32-d chunk: compute -> LDS (XOR-swizzled, conflict-free) -> coalesced
    // global write of hi/lo bf16.
    auto chunk = [&](int d0, int e0, int cnt, float scale,
                     unsigned short* oh, unsigned short* ol) {
        for (int c = 0; c < 32; ++c) {
            float v = 0.f;
            if (c < cnt) v = dot(e0 + c) * scale;
            tile[tid * 32 + (c ^ (tid & 31))] = bf16pack(v);
        }
        __syncthreads();
        for (int p = 0; p < 32; ++p) {
            int idx = p * 256 + tid;
            int rr = idx >> 5, cc = idx & 31;
            unsigned v = tile[rr * 32 + (cc ^ (rr & 31))];
            size_t o = (size_t)(r0 + rr) * DPAD + d0 + cc;
            oh[o] = (unsigned short)(v >> 16);
            ol[o] = (unsigned short)(v & 0xffffu);
        }
        __syncthreads();
    };

    chunk(0,  0,  32, 1.f / 7.f, qh, ql);
    chunk(32, 32, 17, 1.f / 7.f, qh, ql);
    chunk(0,  49, 32, 1.f,       kh, kl);
    chunk(32, 81, 17, 1.f,       kh, kl);

    float wacc = 0.f;
    for (int e = 98; e < E3; ++e) wacc = fmaf(dot(e), Wout[e - 98], wacc);
    wv[r] = wacc;
}

// ---------------------------------------------------------------------------
// Stage B: flash attention with scalar value w, MFMA scores (hi/lo bf16 x3),
// no-max softmax (scores provably bounded ~|17|, fp32 exp sums safe).
// Block = 256 threads (4 waves), f-tile 128; K-tile (32g, hi+lo interleaved,
// XOR-swizzled rows of 256B) double-buffered in LDS via reg-staging.
// ---------------------------------------------------------------------------
__global__ __launch_bounds__(256, 4) void attn_kernel(
    const unsigned short* __restrict__ qh, const unsigned short* __restrict__ ql,
    const unsigned short* __restrict__ kh, const unsigned short* __restrict__ kl,
    const float* __restrict__ wv,
    float* __restrict__ partL, float* __restrict__ partA)
{
    __shared__ __align__(16) unsigned char Kt[2][8192];

    // XCD-chunked swizzle: 1024 blocks, 128 consecutive logical ids per XCD
    // -> each XCD works on 4 consecutive b (its 4MB K/Q panel set L2-fits).
    const int bid = blockIdx.x;
    const int L = (bid & 7) * 128 + (bid >> 3);
    const int b  = L >> 5;          // 0..31
    const int rr = L & 31;
    const int ft = rr >> 1;         // 0..15
    const int sp = rr & 1;          // 0..1

    const int tid  = threadIdx.x;
    const int lane = tid & 63;
    const int wid  = tid >> 6;
    const int col  = lane & 31;     // f (B cols) for MFMA-D; g-row for A frags
    const int half = lane >> 5;
    const int fbase  = ft * FBLK + wid * 32;
    const int gstart = sp * (FF / SPLIT);
    const size_t bq = (size_t)b * FF;

    // Q fragments (hi/lo), hoisted: B-operand col = fbase+col.
    bf16x8 qhf[4], qlf[4];
    {
        const size_t qrow = (bq + fbase + col) * DPAD;
        #pragma unroll
        for (int ks = 0; ks < 4; ++ks) {
            size_t o = qrow + ks * 16 + half * 8;
            qhf[ks] = *(const bf16x8*)(qh + o);
            qlf[ks] = *(const bf16x8*)(ql + o);
        }
    }

    // Staging geometry: LDS row = g-row (stride 256B) = [hi 8 chunks][lo 8],
    // chunk stored at position c ^ (row&15)  (16-slot XOR -> 2-way reads).
    // Each wave stages 2 KB = 2 per-lane 16B loads.
    const int D0 = (wid * 2) * 1024 + lane * 16;
    const int D1 = D0 + 1024;
    const int row0 = D0 >> 8, row1 = D1 >> 8;
    const int c0 = ((D0 >> 4) & 15) ^ (row0 & 15);
    const int c1 = ((D1 >> 4) & 15) ^ (row1 & 15);
    const unsigned short* sb0 = (c0 < 8) ? kh : kl;
    const unsigned short* sb1 = (c1 < 8) ? kh : kl;
    const int so0 = (c0 & 7) * 8, so1 = (c1 & 7) * 8;

    float lsum = 0.f, asum = 0.f;

    uint4 st0 = *(const uint4*)(sb0 + (bq + gstart + row0) * DPAD + so0);
    uint4 st1 = *(const uint4*)(sb1 + (bq + gstart + row1) * DPAD + so1);

    const int rbase = col << 8;     // this lane's A-frag LDS row base
    const int r15 = col & 15;

    for (int t = 0; t < NSTEP; ++t) {
        const int buf = t & 1;
        const int gcur = gstart + t * GSTEP;

        *(uint4*)(&Kt[buf][D0]) = st0;
        *(uint4*)(&Kt[buf][D1]) = st1;
        if (t + 1 < NSTEP) {
            const int gn = gcur + GSTEP;
            st0 = *(const uint4*)(sb0 + (bq + gn + row0) * DPAD + so0);
            st1 = *(const uint4*)(sb1 + (bq + gn + row1) * DPAD + so1);
        }
        __syncthreads();

        f32x16 acc;
        #pragma unroll
        for (int i = 0; i < 16; ++i) acc[i] = 0.f;

        #pragma unroll
        for (int ks = 0; ks < 4; ++ks) {
            const int ch = ks * 2 + half;
            bf16x8 khf = *(const bf16x8*)(&Kt[buf][rbase + ((ch ^ r15) << 4)]);
            bf16x8 klf = *(const bf16x8*)(&Kt[buf][rbase + (((8 + ch) ^ r15) << 4)]);
            acc = __builtin_amdgcn_mfma_f32_32x32x16_bf16(khf, qlf[ks], acc, 0, 0, 0);
            acc = __builtin_amdgcn_mfma_f32_32x32x16_bf16(klf, qhf[ks], acc, 0, 0, 0);
            acc = __builtin_amdgcn_mfma_f32_32x32x16_bf16(khf, qhf[ks], acc, 0, 0, 0);
        }

        // softmax accumulation; D row g = (reg&3) + 8*(reg>>2) + 4*half
        const float* wp = wv + bq + gcur + 4 * half;
        #pragma unroll
        for (int q = 0; q < 4; ++q) {
            float4 w4 = *(const float4*)(wp + q * 8);
            float p0 = __expf(acc[q * 4 + 0]);
            float p1 = __expf(acc[q * 4 + 1]);
            float p2 = __expf(acc[q * 4 + 2]);
            float p3 = __expf(acc[q * 4 + 3]);
            lsum += ((p0 + p1) + (p2 + p3));
            asum = fmaf(p0, w4.x, fmaf(p1, w4.y, fmaf(p2, w4.z, fmaf(p3, w4.w, asum))));
        }
        // next iter writes buf^1; its readers finished before THIS barrier.
    }

    lsum += __shfl_xor(lsum, 32);
    asum += __shfl_xor(asum, 32);
    if (half == 0) {
        size_t o = ((size_t)sp * BB + b) * FF + fbase + col;
        partL[o] = lsum;
        partA[o] = asum;
    }
}

// ---------------------------------------------------------------------------
// Stage C: combine split partials, then BatchNorm over batch per channel f.
// ---------------------------------------------------------------------------
__global__ __launch_bounds__(256) void bn_kernel(
    const float* __restrict__ partL, const float* __restrict__ partA,
    const float* __restrict__ gamma, const float* __restrict__ beta,
    float* __restrict__ out)
{
    const int f = blockIdx.x * 256 + threadIdx.x;
    float v[BB];
    float mean = 0.f;
    #pragma unroll
    for (int b = 0; b < BB; ++b) {
        float l = partL[(size_t)b * FF + f] + partL[(size_t)(BB + b) * FF + f];
        float a = partA[(size_t)b * FF + f] + partA[(size_t)(BB + b) * FF + f];
        v[b] = a / l;
        mean += v[b];
    }
    mean *= (1.f / BB);
    float var = 0.f;
    #pragma unroll
    for (int b = 0; b < BB; ++b) {
        float d = v[b] - mean;
        var = fmaf(d, d, var);
    }
    var *= (1.f / BB);
    const float inv = rsqrtf(var + 1e-5f);
    const float g = gamma[f], be = beta[f];
    #pragma unroll
    for (int b = 0; b < BB; ++b)
        out[((size_t)b << 11) + f] = (v[b] - mean) * inv * g + be;
}

// ---------------------------------------------------------------------------
extern "C" void kernel_launch(void* const* d_in, const int* in_sizes, int n_in,
                              void* d_out, int out_size, void* d_ws, size_t ws_size,
                              hipStream_t stream)
{
    const float* x     = (const float*)d_in[0];
    const float* Wqkv  = (const float*)d_in[1];
    const float* Wout  = (const float*)d_in[2];
    // d_in[3] = b_out: cancels exactly under BatchNorm mean subtraction.
    const float* gamma = (const float*)d_in[4];
    const float* beta  = (const float*)d_in[5];

    char* wsb = (char*)d_ws;
    const size_t PANEL = (size_t)BB * FF * DPAD * sizeof(unsigned short); // 8 MB
    unsigned short* qh = (unsigned short*)(wsb);
    unsigned short* ql = (unsigned short*)(wsb + PANEL);
    unsigned short* kh = (unsigned short*)(wsb + 2 * PANEL);
    unsigned short* kl = (unsigned short*)(wsb + 3 * PANEL);
    float* wv    = (float*)(wsb + 4 * PANEL);
    float* partL = (float*)(wsb + 4 * PANEL + 256 * 1024);
    float* partA = (float*)(wsb + 4 * PANEL + 256 * 1024 + SPLIT * BB * FF * 4);
    // total ws use ~= 33.3 MB

    qkvw_kernel<<<dim3((BB * FF) / 256), dim3(256), 0, stream>>>(
        x, Wqkv, Wout, qh, ql, kh, kl, wv);

    attn_kernel<<<dim3(BB * (FF / FBLK) * SPLIT), dim3(256), 0, stream>>>(
        qh, ql, kh, kl, wv, partL, partA);

    bn_kernel<<<dim3(FF / 256), dim3(256), 0, stream>>>(
        partL, partA, gamma, beta, (float*)d_out);
}